// Round 1
// baseline (451.538 us; speedup 1.0000x reference)
//
#include <hip/hip_runtime.h>
#include <cmath>

#define NB 64
#define ND 1024
#define DH 512
#define NL 2048
#define NCHUNK 16
#define RPB 128   // rows per block (L / NCHUNK)
#define RPW 32    // rows per wave (RPB / 4 waves)
#define REC 520   // floats per (b,chunk,k) partial record: [M, L, pad, pad, acc[512], pad]

// ---------------------------------------------------------------------------
// Small GEMM: out[b][j] = act( sum_m A[b][m] * W[j][m] ), A:[64,K], W:[1024,K]
// Block = all 64 b x 4 j, LDS-tiled over m in steps of 64. Pad 65 => scalar
// LDS reads conflict-free (stride 65 % 32 = 1, 2 lanes/bank = free).
// ---------------------------------------------------------------------------
__global__ __launch_bounds__(256) void k_gemm(const float* __restrict__ A,
                                              const float* __restrict__ W,
                                              float* __restrict__ out,
                                              int K, int do_tanh) {
  __shared__ float As[64][65];
  __shared__ float Ws[4][65];
  const int t = threadIdx.x;
  const int jt = blockIdx.x * 4;
  const int b = t & 63, jl = t >> 6;
  float acc = 0.f;
  for (int m0 = 0; m0 < K; m0 += 64) {
#pragma unroll
    for (int i = 0; i < 4; i++) {
      int f = t + i * 256;                // 1024 float4 slots over [64][16]
      int r = f >> 4, c = (f & 15) * 4;
      const float4 v = *(const float4*)(A + (size_t)r * K + m0 + c);
      As[r][c] = v.x; As[r][c + 1] = v.y; As[r][c + 2] = v.z; As[r][c + 3] = v.w;
    }
    if (t < 64) {
      int r = t >> 4, c = (t & 15) * 4;
      const float4 v = *(const float4*)(W + (size_t)(jt + r) * K + m0 + c);
      Ws[r][c] = v.x; Ws[r][c + 1] = v.y; Ws[r][c + 2] = v.z; Ws[r][c + 3] = v.w;
    }
    __syncthreads();
#pragma unroll
    for (int mm = 0; mm < 64; mm++) acc += As[b][mm] * Ws[jl][mm];
    __syncthreads();
  }
  out[(size_t)b * ND + jt + jl] = do_tanh ? tanhf(acc) : acc;
}

// ---------------------------------------------------------------------------
// Fused attention pass: reads context ONCE. Per (b, chunk) block, per wave:
// 32 rows; each row: dual dot (k=0/1) via lane-sliced FMA + butterfly
// allreduce, online softmax (m,l) + rescaled weighted accumulation in regs.
// Raw scores -> d_out attn region (normalized later by k3).
// Per-block wave merge via LDS -> partial record {M, L, acc[512]} per k.
// ---------------------------------------------------------------------------
__global__ __launch_bounds__(256, 4) void k2_attn(const float* __restrict__ ctx,
                                                  const float* __restrict__ tgt,
                                                  float* __restrict__ sc0,
                                                  float* __restrict__ sc1,
                                                  float* __restrict__ part) {
  const int chunk = blockIdx.x, b = blockIdx.y;
  const int wave = threadIdx.x >> 6, lane = threadIdx.x & 63;
  const float* crow = ctx + ((size_t)b * NL + chunk * RPB + wave * RPW) * DH + lane * 8;

  // Lane owns d = 8*lane + j (j=0..7). target row is interleaved (2d+k).
  float t0[8], t1[8];
  {
    const float* tp = tgt + b * ND + lane * 16;
#pragma unroll
    for (int j = 0; j < 4; j++) {
      float4 v = *(const float4*)(tp + j * 4);
      t0[2 * j] = v.x; t1[2 * j] = v.y; t0[2 * j + 1] = v.z; t1[2 * j + 1] = v.w;
    }
  }

  float m0 = -INFINITY, l0 = 0.f, m1 = -INFINITY, l1 = 0.f;
  float a0[8], a1[8];
#pragma unroll
  for (int j = 0; j < 8; j++) { a0[j] = 0.f; a1[j] = 0.f; }
  float sv0 = 0.f, sv1 = 0.f;

  float4 pa = *(const float4*)(crow);
  float4 pb = *(const float4*)(crow + 4);
#pragma unroll 2
  for (int i = 0; i < RPW; i++) {
    float c[8] = {pa.x, pa.y, pa.z, pa.w, pb.x, pb.y, pb.z, pb.w};
    if (i + 1 < RPW) {   // depth-1 register prefetch of next row
      pa = *(const float4*)(crow + (size_t)(i + 1) * DH);
      pb = *(const float4*)(crow + (size_t)(i + 1) * DH + 4);
    }
    float s0 = 0.f, s1 = 0.f;
#pragma unroll
    for (int j = 0; j < 8; j++) { s0 += c[j] * t0[j]; s1 += c[j] * t1[j]; }
#pragma unroll
    for (int off = 32; off > 0; off >>= 1) {
      s0 += __shfl_xor(s0, off);
      s1 += __shfl_xor(s1, off);
    }
    if (lane == i) { sv0 = s0; sv1 = s1; }   // park raw score for row i
    // s0/s1/m0/m1 are wave-uniform -> uniform branches (cheap skip)
    if (s0 > m0) {
      float al = __expf(m0 - s0);
      m0 = s0; l0 *= al;
#pragma unroll
      for (int j = 0; j < 8; j++) a0[j] *= al;
    }
    {
      float p = __expf(s0 - m0);
      l0 += p;
#pragma unroll
      for (int j = 0; j < 8; j++) a0[j] += p * c[j];
    }
    if (s1 > m1) {
      float al = __expf(m1 - s1);
      m1 = s1; l1 *= al;
#pragma unroll
      for (int j = 0; j < 8; j++) a1[j] *= al;
    }
    {
      float p = __expf(s1 - m1);
      l1 += p;
#pragma unroll
      for (int j = 0; j < 8; j++) a1[j] += p * c[j];
    }
  }

  const int rowbase = b * NL + chunk * RPB + wave * RPW;
  if (lane < RPW) { sc0[rowbase + lane] = sv0; sc1[rowbase + lane] = sv1; }

  // merge 4 waves in LDS
  __shared__ float accS[4][1024];
  __shared__ float mlS[4][4];
#pragma unroll
  for (int j = 0; j < 8; j++) {
    accS[wave][lane * 8 + j] = a0[j];
    accS[wave][512 + lane * 8 + j] = a1[j];
  }
  if (lane == 0) { mlS[wave][0] = m0; mlS[wave][1] = l0; mlS[wave][2] = m1; mlS[wave][3] = l1; }
  __syncthreads();

  const int t = threadIdx.x;
  const int k = (t * 4) >> 9;        // t<128 -> k=0, else k=1
  const int d = (t * 4) & 511;
  float M = fmaxf(fmaxf(mlS[0][2 * k], mlS[1][2 * k]), fmaxf(mlS[2][2 * k], mlS[3][2 * k]));
  float Lk = 0.f;
  float v0 = 0.f, v1 = 0.f, v2 = 0.f, v3 = 0.f;
#pragma unroll
  for (int w = 0; w < 4; w++) {
    float e = __expf(mlS[w][2 * k] - M);
    Lk += mlS[w][2 * k + 1] * e;
    const float* ap = &accS[w][k * 512 + d];
    v0 += ap[0] * e; v1 += ap[1] * e; v2 += ap[2] * e; v3 += ap[3] * e;
  }
  float* rec = part + ((size_t)(b * NCHUNK + chunk) * 2 + k) * REC;
  if ((t & 127) == 0) { rec[0] = M; rec[1] = Lk; }
  rec[4 + d] = v0; rec[5 + d] = v1; rec[6 + d] = v2; rec[7 + d] = v3;
}

// ---------------------------------------------------------------------------
// Per-batch merge of NCHUNK partials -> combined row [w0|w1|input], plus
// in-place normalization of raw scores into final attn probabilities.
// ---------------------------------------------------------------------------
__global__ __launch_bounds__(256) void k3_combine(const float* __restrict__ part,
                                                  const float* __restrict__ inp,
                                                  float* __restrict__ combined,
                                                  float* __restrict__ sc0,
                                                  float* __restrict__ sc1) {
  const int b = blockIdx.x;
  const int t = threadIdx.x;
  __shared__ float MM[2], LL[2];
  if (t < 2) {
    const int k = t;
    float Mk = -INFINITY;
    for (int c = 0; c < NCHUNK; c++)
      Mk = fmaxf(Mk, part[((size_t)(b * NCHUNK + c) * 2 + k) * REC]);
    float Lk = 0.f;
    for (int c = 0; c < NCHUNK; c++) {
      const float* rec = part + ((size_t)(b * NCHUNK + c) * 2 + k) * REC;
      Lk += rec[1] * __expf(rec[0] - Mk);
    }
    MM[k] = Mk; LL[k] = Lk;
  }
  __syncthreads();

  const int k = (t * 4) >> 9, d = (t * 4) & 511;
  float v0 = 0.f, v1 = 0.f, v2 = 0.f, v3 = 0.f;
  for (int c = 0; c < NCHUNK; c++) {
    const float* rec = part + ((size_t)(b * NCHUNK + c) * 2 + k) * REC;
    float e = __expf(rec[0] - MM[k]);
    v0 += rec[4 + d] * e; v1 += rec[5 + d] * e; v2 += rec[6 + d] * e; v3 += rec[7 + d] * e;
  }
  const float inv = 1.f / LL[k];
  float* cp = combined + (size_t)b * 2048 + k * 512 + d;
  cp[0] = v0 * inv; cp[1] = v1 * inv; cp[2] = v2 * inv; cp[3] = v3 * inv;

  // combined[.., 1024..2047] = input row
  const float4 iv = *(const float4*)(inp + (size_t)b * ND + t * 4);
  *(float4*)(combined + (size_t)b * 2048 + 1024 + t * 4) = iv;

  // normalize raw scores in place -> attn outputs
  const float M0 = MM[0], i0 = 1.f / LL[0];
  const float M1 = MM[1], i1 = 1.f / LL[1];
#pragma unroll
  for (int r = 0; r < 8; r++) {
    const int idx = b * NL + t * 8 + r;
    sc0[idx] = __expf(sc0[idx] - M0) * i0;
    sc1[idx] = __expf(sc1[idx] - M1) * i1;
  }
}

// ---------------------------------------------------------------------------
extern "C" void kernel_launch(void* const* d_in, const int* in_sizes, int n_in,
                              void* d_out, int out_size, void* d_ws, size_t ws_size,
                              hipStream_t stream) {
  const float* input   = (const float*)d_in[0];   // [64,1024]
  const float* context = (const float*)d_in[1];   // [64,2048,512]
  const float* W_in    = (const float*)d_in[2];   // [1024,1024]
  const float* W_out   = (const float*)d_in[3];   // [1024,2048]

  float* out   = (float*)d_out;        // [64,1024] contextOutput
  float* attn0 = out + NB * ND;        // [64,2048]
  float* attn1 = attn0 + NB * NL;      // [64,2048]

  float* ws       = (float*)d_ws;
  float* target   = ws;                          // 64*1024
  float* combined = ws + NB * ND;                // 64*2048
  float* part     = ws + NB * ND + NB * 2048;    // 64*16*2*520 floats

  // 1) target = input @ W_in.T
  k_gemm<<<dim3(ND / 4), dim3(256), 0, stream>>>(input, W_in, target, ND, 0);
  // 2) fused scores + online-softmax weighted partials (context read once)
  k2_attn<<<dim3(NCHUNK, NB), dim3(256), 0, stream>>>(context, target, attn0, attn1, part);
  // 3) merge partials -> combined rows; normalize attn in place
  k3_combine<<<dim3(NB), dim3(256), 0, stream>>>(part, input, combined, attn0, attn1);
  // 4) contextOutput = tanh(combined @ W_out.T)
  k_gemm<<<dim3(ND / 4), dim3(256), 0, stream>>>(combined, W_out, out, 2 * ND, 1);
}